// Round 1
// baseline (9150.139 us; speedup 1.0000x reference)
//
#include <hip/hip_runtime.h>

#define N_NODES 100000
#define N_EDGES 1600000
#define C_DIM 128
#define EC_DIM 16
#define L_LAYERS 3
#define G_GRAPHS 256
#define GN_EPS 1e-5f

__device__ __forceinline__ float silu_f(float v) {
    return v / (1.0f + __expf(-v));
}

__device__ __forceinline__ float4 ld4(const float* p) { return *(const float4*)p; }
__device__ __forceinline__ void st4(float* p, float4 v) { *(float4*)p = v; }
__device__ __forceinline__ float4 fma4(float s, float4 w, float4 a) {
    a.x = fmaf(s, w.x, a.x); a.y = fmaf(s, w.y, a.y);
    a.z = fmaf(s, w.z, a.z); a.w = fmaf(s, w.w, a.w);
    return a;
}

// ---------------- graph bookkeeping ----------------

__global__ void zero_cnt_kernel(int* cnt) { cnt[threadIdx.x] = 0; }

__global__ void count_kernel(const int* __restrict__ batch, int* __restrict__ cnt) {
    int i = blockIdx.x * blockDim.x + threadIdx.x;
    if (i < N_NODES) atomicAdd(&cnt[batch[i]], 1);
}

// 1 block of 256 threads: exclusive scan of per-graph counts (batch is sorted)
__global__ void scan_kernel(const int* __restrict__ cnt, int* __restrict__ start,
                            float* __restrict__ cntf) {
    __shared__ int s[G_GRAPHS];
    int t = threadIdx.x;
    int v = cnt[t];
    s[t] = v;
    __syncthreads();
    for (int off = 1; off < G_GRAPHS; off <<= 1) {
        int add = (t >= off) ? s[t - off] : 0;
        __syncthreads();
        s[t] += add;
        __syncthreads();
    }
    start[t] = s[t] - v;   // exclusive prefix
    cntf[t] = (float)v;
}

// ---------------- fused edge-GEMM + message + scatter ----------------
// 32 threads per edge, 4 channels/thread. W_edge (16x128) lives in 64 VGPRs,
// amortized over a grid-stride edge loop. hb is pre-initialized with x so the
// atomic adds produce h = x + aggr directly.
__global__ __launch_bounds__(256) void scatter_kernel(
    const float* __restrict__ x, const float* __restrict__ ea,
    const int* __restrict__ eidx, const float* __restrict__ W,
    const float* __restrict__ bias, float* __restrict__ hb)
{
    const int lane = threadIdx.x & 31;
    const int c4 = lane * 4;
    float4 wr[EC_DIM];
#pragma unroll
    for (int k = 0; k < EC_DIM; ++k) wr[k] = ld4(W + k * C_DIM + c4);
    const float4 b4 = ld4(bias + c4);

    int eg = (blockIdx.x * blockDim.x + threadIdx.x) >> 5;
    const int stride = (gridDim.x * blockDim.x) >> 5;
    for (int e = eg; e < N_EDGES; e += stride) {
        const int src = eidx[e];
        const int dst = eidx[N_EDGES + e];
        const float4* eap = (const float4*)(ea + (size_t)e * EC_DIM);
        float4 a0 = eap[0], a1 = eap[1], a2 = eap[2], a3 = eap[3];
        float4 acc = b4;
        acc = fma4(a0.x, wr[0], acc);  acc = fma4(a0.y, wr[1], acc);
        acc = fma4(a0.z, wr[2], acc);  acc = fma4(a0.w, wr[3], acc);
        acc = fma4(a1.x, wr[4], acc);  acc = fma4(a1.y, wr[5], acc);
        acc = fma4(a1.z, wr[6], acc);  acc = fma4(a1.w, wr[7], acc);
        acc = fma4(a2.x, wr[8], acc);  acc = fma4(a2.y, wr[9], acc);
        acc = fma4(a2.z, wr[10], acc); acc = fma4(a2.w, wr[11], acc);
        acc = fma4(a3.x, wr[12], acc); acc = fma4(a3.y, wr[13], acc);
        acc = fma4(a3.z, wr[14], acc); acc = fma4(a3.w, wr[15], acc);
        acc.x = silu_f(acc.x); acc.y = silu_f(acc.y);
        acc.z = silu_f(acc.z); acc.w = silu_f(acc.w);
        const float4 xs = ld4(x + (size_t)src * C_DIM + c4);
        const float m0 = fmaxf(xs.x + acc.x, 0.0f);
        const float m1 = fmaxf(xs.y + acc.y, 0.0f);
        const float m2 = fmaxf(xs.z + acc.z, 0.0f);
        const float m3 = fmaxf(xs.w + acc.w, 0.0f);
        float* hp = hb + (size_t)dst * C_DIM + c4;
        atomicAdd(hp + 0, m0);
        atomicAdd(hp + 1, m1);
        atomicAdd(hp + 2, m2);
        atomicAdd(hp + 3, m3);
    }
}

// ---------------- fp32 GEMM: out[N,128] = act(A[N,128] @ W[128,128] + b) ----
// W in 64KB LDS (2 blocks/CU). 32 rows/block; thread = 4 rows x 4 cols.
// A values broadcast-load from global (L1-served, same addr across 32 lanes).
template<bool SILU>
__global__ __launch_bounds__(256) void gemm128_kernel(
    const float* __restrict__ A, const float* __restrict__ W,
    const float* __restrict__ bias, float* __restrict__ out)
{
    __shared__ float Wl[C_DIM * C_DIM];   // 64 KB
    const int tid = threadIdx.x;
    const int rowbase = blockIdx.x * 32;
#pragma unroll
    for (int i = 0; i < 16; ++i)
        ((float4*)Wl)[i * 256 + tid] = ((const float4*)W)[i * 256 + tid];
    __syncthreads();

    const int cx = tid & 31;        // col group: channels [cx*4, cx*4+4)
    const int ry = tid >> 5;        // row group: rows ry*4 .. ry*4+3
    const float4 bias4 = ld4(bias + cx * 4);
    float4 acc[4] = {bias4, bias4, bias4, bias4};
    const float* Ab = A + (size_t)(rowbase + ry * 4) * C_DIM;

    for (int k = 0; k < C_DIM; k += 4) {
        float4 a[4], w[4];
#pragma unroll
        for (int rr = 0; rr < 4; ++rr) a[rr] = ld4(Ab + rr * C_DIM + k);
#pragma unroll
        for (int kk = 0; kk < 4; ++kk) w[kk] = *(const float4*)&Wl[(k + kk) * C_DIM + cx * 4];
#pragma unroll
        for (int rr = 0; rr < 4; ++rr) {
            acc[rr] = fma4(a[rr].x, w[0], acc[rr]);
            acc[rr] = fma4(a[rr].y, w[1], acc[rr]);
            acc[rr] = fma4(a[rr].z, w[2], acc[rr]);
            acc[rr] = fma4(a[rr].w, w[3], acc[rr]);
        }
    }
#pragma unroll
    for (int rr = 0; rr < 4; ++rr) {
        float4 v = acc[rr];
        if (SILU) { v.x = silu_f(v.x); v.y = silu_f(v.y); v.z = silu_f(v.z); v.w = silu_f(v.w); }
        st4(out + (size_t)(rowbase + ry * 4 + rr) * C_DIM + cx * 4, v);
    }
}

// ---------------- GraphNorm: one-pass stats ----------------
// var(out) = E[h^2] - (2s - s^2) * mean^2  since out = h - mean*s (uncentered
// second moment per the reference). Stores mean*s and 1/sqrt(var+eps).
__global__ __launch_bounds__(256) void gn_reduce_kernel(
    const float* __restrict__ h, const int* __restrict__ start,
    const int* __restrict__ cnt, const float* __restrict__ cntf,
    const float* __restrict__ ms, float* __restrict__ meansc,
    float* __restrict__ rstd)
{
    const int g = blockIdx.x;
    const int c = threadIdx.x & 127;
    const int half = threadIdx.x >> 7;
    const int s0 = start[g];
    const int n = cnt[g];
    float sum = 0.f, sq = 0.f;
    for (int r = half; r < n; r += 2) {
        float v = h[(size_t)(s0 + r) * C_DIM + c];
        sum += v; sq += v * v;
    }
    __shared__ float ls[256], lq[256];
    ls[threadIdx.x] = sum; lq[threadIdx.x] = sq;
    __syncthreads();
    if (threadIdx.x < 128) {
        sum = ls[threadIdx.x] + ls[threadIdx.x + 128];
        sq  = lq[threadIdx.x] + lq[threadIdx.x + 128];
        const float cn = cntf[g];
        const float mean = sum / cn;
        const float msq = sq / cn;
        const float s = ms[c];
        const float var = msq - (2.0f * s - s * s) * mean * mean;
        meansc[(size_t)g * C_DIM + c] = mean * s;
        rstd[(size_t)g * C_DIM + c] = 1.0f / sqrtf(var + GN_EPS);
    }
}

// Normalize; also primes next layer's h-buffer (h_next = x_new) when hnext!=0,
// replacing a d2d memcpy.
__global__ __launch_bounds__(256) void gn_norm_kernel(
    const float* __restrict__ h, const int* __restrict__ batch,
    const float* __restrict__ meansc, const float* __restrict__ rstd,
    const float* __restrict__ gw, const float* __restrict__ gb,
    float* __restrict__ out, float* __restrict__ hnext)
{
    const int id = blockIdx.x * blockDim.x + threadIdx.x;
    const int row = id >> 5;
    const int c4 = (id & 31) * 4;
    if (row >= N_NODES) return;
    const int g = batch[row];
    const float4 hv = ld4(h + (size_t)row * C_DIM + c4);
    const float4 m = ld4(meansc + (size_t)g * C_DIM + c4);
    const float4 r = ld4(rstd + (size_t)g * C_DIM + c4);
    const float4 w = ld4(gw + c4);
    const float4 b = ld4(gb + c4);
    float4 o;
    o.x = fmaf((hv.x - m.x) * r.x, w.x, b.x);
    o.y = fmaf((hv.y - m.y) * r.y, w.y, b.y);
    o.z = fmaf((hv.z - m.z) * r.z, w.z, b.z);
    o.w = fmaf((hv.w - m.w) * r.w, w.w, b.w);
    st4(out + (size_t)row * C_DIM + c4, o);
    if (hnext) st4(hnext + (size_t)row * C_DIM + c4, o);
}

// ---------------- launch ----------------

extern "C" void kernel_launch(void* const* d_in, const int* in_sizes, int n_in,
                              void* d_out, int out_size, void* d_ws, size_t ws_size,
                              hipStream_t stream)
{
    const float* x_in      = (const float*)d_in[0];
    const float* edge_attr = (const float*)d_in[1];
    const int*   edge_idx  = (const int*)d_in[2];
    const int*   batch     = (const int*)d_in[3];
    const float* lew       = (const float*)d_in[4];
    const float* leb       = (const float*)d_in[5];
    const float* w1        = (const float*)d_in[6];
    const float* b1        = (const float*)d_in[7];
    const float* w2        = (const float*)d_in[8];
    const float* b2        = (const float*)d_in[9];
    const float* gnw       = (const float*)d_in[10];
    const float* gnb       = (const float*)d_in[11];
    const float* gms       = (const float*)d_in[12];
    float* out = (float*)d_out;

    float* hbuf   = (float*)d_ws;                       // N*C
    float* meansc = hbuf + (size_t)N_NODES * C_DIM;     // G*C
    float* rstd   = meansc + (size_t)G_GRAPHS * C_DIM;  // G*C
    float* cntf   = rstd + (size_t)G_GRAPHS * C_DIM;    // G
    int*   cnti   = (int*)(cntf + G_GRAPHS);            // G
    int*   startg = cnti + G_GRAPHS;                    // G

    zero_cnt_kernel<<<1, G_GRAPHS, 0, stream>>>(cnti);
    count_kernel<<<(N_NODES + 255) / 256, 256, 0, stream>>>(batch, cnti);
    scan_kernel<<<1, G_GRAPHS, 0, stream>>>(cnti, startg, cntf);

    // layer 0 h-init: h = x (later layers primed by gn_norm_kernel)
    hipMemcpyAsync(hbuf, x_in, (size_t)N_NODES * C_DIM * sizeof(float),
                   hipMemcpyDeviceToDevice, stream);

    const float* cur = x_in;
    for (int l = 0; l < L_LAYERS; ++l) {
        scatter_kernel<<<2048, 256, 0, stream>>>(cur, edge_attr, edge_idx, lew, leb, hbuf);
        gemm128_kernel<true><<<N_NODES / 32, 256, 0, stream>>>(
            hbuf, w1 + (size_t)l * C_DIM * C_DIM, b1 + (size_t)l * C_DIM, out);
        gemm128_kernel<false><<<N_NODES / 32, 256, 0, stream>>>(
            out, w2 + (size_t)l * C_DIM * C_DIM, b2 + (size_t)l * C_DIM, hbuf);
        gn_reduce_kernel<<<G_GRAPHS, 256, 0, stream>>>(
            hbuf, startg, cnti, cntf, gms + (size_t)l * C_DIM, meansc, rstd);
        float* hnext = (l + 1 < L_LAYERS) ? hbuf : nullptr;
        gn_norm_kernel<<<(N_NODES * 32 + 255) / 256, 256, 0, stream>>>(
            hbuf, batch, meansc, rstd, gnw + (size_t)l * C_DIM, gnb + (size_t)l * C_DIM,
            out, hnext);
        cur = out;
    }
}

// Round 2
// 2497.640 us; speedup vs baseline: 3.6635x; 3.6635x over previous
//
#include <hip/hip_runtime.h>

#define N_NODES 100000
#define N_EDGES 1600000
#define C_DIM 128
#define EC_DIM 16
#define L_LAYERS 3
#define G_GRAPHS 256
#define GN_EPS 1e-5f
#define SCAN_BLOCKS 391   // ceil(100000/256)

__device__ __forceinline__ float silu_f(float v) {
    return v / (1.0f + __expf(-v));
}

__device__ __forceinline__ float4 ld4(const float* p) { return *(const float4*)p; }
__device__ __forceinline__ void st4(float* p, float4 v) { *(float4*)p = v; }
__device__ __forceinline__ float4 fma4(float s, float4 w, float4 a) {
    a.x = fmaf(s, w.x, a.x); a.y = fmaf(s, w.y, a.y);
    a.z = fmaf(s, w.z, a.z); a.w = fmaf(s, w.w, a.w);
    return a;
}

// ---------------- graph bookkeeping (GraphNorm segments) ----------------

__global__ void zero_cnt_kernel(int* cnt) { cnt[threadIdx.x] = 0; }

__global__ void count_kernel(const int* __restrict__ batch, int* __restrict__ cnt) {
    int i = blockIdx.x * blockDim.x + threadIdx.x;
    if (i < N_NODES) atomicAdd(&cnt[batch[i]], 1);
}

__global__ void scan_kernel(const int* __restrict__ cnt, int* __restrict__ start,
                            float* __restrict__ cntf) {
    __shared__ int s[G_GRAPHS];
    int t = threadIdx.x;
    int v = cnt[t];
    s[t] = v;
    __syncthreads();
    for (int off = 1; off < G_GRAPHS; off <<= 1) {
        int add = (t >= off) ? s[t - off] : 0;
        __syncthreads();
        s[t] += add;
        __syncthreads();
    }
    start[t] = s[t] - v;
    cntf[t] = (float)v;
}

// ---------------- CSR build (by dst) ----------------

__global__ void deg_count_kernel(const int* __restrict__ eidx, int* __restrict__ deg) {
    int e = blockIdx.x * blockDim.x + threadIdx.x;
    if (e < N_EDGES) atomicAdd(&deg[eidx[N_EDGES + e]], 1);
}

// block-local exclusive scan of 256 degrees; emits block sums
__global__ void scanA_kernel(const int* __restrict__ deg, int* __restrict__ rpl,
                             int* __restrict__ bsum) {
    __shared__ int s[256];
    int i = blockIdx.x * 256 + threadIdx.x;
    int v = (i < N_NODES) ? deg[i] : 0;
    s[threadIdx.x] = v;
    __syncthreads();
    for (int off = 1; off < 256; off <<= 1) {
        int add = (threadIdx.x >= off) ? s[threadIdx.x - off] : 0;
        __syncthreads();
        s[threadIdx.x] += add;
        __syncthreads();
    }
    if (i < N_NODES) rpl[i] = s[threadIdx.x] - v;
    if (threadIdx.x == 255) bsum[blockIdx.x] = s[255];
}

// 1 block, 512 threads: exclusive scan of the 391 block sums
__global__ void scanB_kernel(const int* __restrict__ bsum, int* __restrict__ boff) {
    __shared__ int s[512];
    int t = threadIdx.x;
    int v = (t < SCAN_BLOCKS) ? bsum[t] : 0;
    s[t] = v;
    __syncthreads();
    for (int off = 1; off < 512; off <<= 1) {
        int add = (t >= off) ? s[t - off] : 0;
        __syncthreads();
        s[t] += add;
        __syncthreads();
    }
    if (t < SCAN_BLOCKS) boff[t] = s[t] - v;
}

__global__ void scanC_kernel(const int* __restrict__ rpl, const int* __restrict__ boff,
                             int* __restrict__ rp, int* __restrict__ cursor) {
    int i = blockIdx.x * 256 + threadIdx.x;
    if (i < N_NODES) {
        int v = rpl[i] + boff[blockIdx.x];
        rp[i] = v;
        cursor[i] = v;
    }
    if (i == 0) rp[N_NODES] = N_EDGES;
}

__global__ void fill_kernel(const int* __restrict__ eidx, int* __restrict__ cursor,
                            int2* __restrict__ csr) {
    int e = blockIdx.x * blockDim.x + threadIdx.x;
    if (e >= N_EDGES) return;
    int src = eidx[e];
    int dst = eidx[N_EDGES + e];
    int pos = atomicAdd(&cursor[dst], 1);
    csr[pos] = make_int2(src, e);
}

// ---------------- gather: h[n] = x[n] + sum_{e->n} relu(x[src]+silu(ea@W+b)) ----
// One wave (64 lanes) per node; lane owns 2 channels. W_edge slice in 32 VGPRs.
__device__ __forceinline__ float2 proj_edge(const float4* eap, const float2* wr, float2 b2) {
    float4 a0 = eap[0], a1 = eap[1], a2 = eap[2], a3 = eap[3];
    float av[16] = {a0.x, a0.y, a0.z, a0.w, a1.x, a1.y, a1.z, a1.w,
                    a2.x, a2.y, a2.z, a2.w, a3.x, a3.y, a3.z, a3.w};
    float px = b2.x, py = b2.y;
#pragma unroll
    for (int k = 0; k < 16; ++k) {
        px = fmaf(av[k], wr[k].x, px);
        py = fmaf(av[k], wr[k].y, py);
    }
    return make_float2(silu_f(px), silu_f(py));
}

__global__ __launch_bounds__(256) void gather_kernel(
    const float* __restrict__ x, const float* __restrict__ ea,
    const int2* __restrict__ csr, const int* __restrict__ rp,
    const float* __restrict__ W, const float* __restrict__ bias,
    float* __restrict__ hb)
{
    const int n = (blockIdx.x * blockDim.x + threadIdx.x) >> 6;
    if (n >= N_NODES) return;
    const int lane = threadIdx.x & 63;
    const int c2 = lane * 2;

    float2 wr[EC_DIM];
#pragma unroll
    for (int k = 0; k < EC_DIM; ++k) wr[k] = *(const float2*)(W + k * C_DIM + c2);
    const float2 b2 = *(const float2*)(bias + c2);

    float accx = 0.f, accy = 0.f;
    const int beg = rp[n], end = rp[n + 1];
    int j = beg;
    for (; j + 2 <= end; j += 2) {
        int2 se0 = csr[j];
        int2 se1 = csr[j + 1];
        const float4* ep0 = (const float4*)(ea + (size_t)se0.y * EC_DIM);
        const float4* ep1 = (const float4*)(ea + (size_t)se1.y * EC_DIM);
        float2 xs0 = *(const float2*)(x + (size_t)se0.x * C_DIM + c2);
        float2 xs1 = *(const float2*)(x + (size_t)se1.x * C_DIM + c2);
        float2 p0 = proj_edge(ep0, wr, b2);
        float2 p1 = proj_edge(ep1, wr, b2);
        accx += fmaxf(xs0.x + p0.x, 0.f) + fmaxf(xs1.x + p1.x, 0.f);
        accy += fmaxf(xs0.y + p0.y, 0.f) + fmaxf(xs1.y + p1.y, 0.f);
    }
    if (j < end) {
        int2 se = csr[j];
        const float4* ep = (const float4*)(ea + (size_t)se.y * EC_DIM);
        float2 xs = *(const float2*)(x + (size_t)se.x * C_DIM + c2);
        float2 p = proj_edge(ep, wr, b2);
        accx += fmaxf(xs.x + p.x, 0.f);
        accy += fmaxf(xs.y + p.y, 0.f);
    }
    const float2 xo = *(const float2*)(x + (size_t)n * C_DIM + c2);
    float2 o = make_float2(xo.x + accx, xo.y + accy);
    *(float2*)(hb + (size_t)n * C_DIM + c2) = o;
}

// ---------------- fp32 GEMM: out[N,128] = act(A[N,128] @ W[128,128] + b) ----
template<bool SILU>
__global__ __launch_bounds__(256) void gemm128_kernel(
    const float* __restrict__ A, const float* __restrict__ W,
    const float* __restrict__ bias, float* __restrict__ out)
{
    __shared__ float Wl[C_DIM * C_DIM];   // 64 KB
    const int tid = threadIdx.x;
    const int rowbase = blockIdx.x * 32;
#pragma unroll
    for (int i = 0; i < 16; ++i)
        ((float4*)Wl)[i * 256 + tid] = ((const float4*)W)[i * 256 + tid];
    __syncthreads();

    const int cx = tid & 31;
    const int ry = tid >> 5;
    const float4 bias4 = ld4(bias + cx * 4);
    float4 acc[4] = {bias4, bias4, bias4, bias4};
    const float* Ab = A + (size_t)(rowbase + ry * 4) * C_DIM;

    for (int k = 0; k < C_DIM; k += 4) {
        float4 a[4], w[4];
#pragma unroll
        for (int rr = 0; rr < 4; ++rr) a[rr] = ld4(Ab + rr * C_DIM + k);
#pragma unroll
        for (int kk = 0; kk < 4; ++kk) w[kk] = *(const float4*)&Wl[(k + kk) * C_DIM + cx * 4];
#pragma unroll
        for (int rr = 0; rr < 4; ++rr) {
            acc[rr] = fma4(a[rr].x, w[0], acc[rr]);
            acc[rr] = fma4(a[rr].y, w[1], acc[rr]);
            acc[rr] = fma4(a[rr].z, w[2], acc[rr]);
            acc[rr] = fma4(a[rr].w, w[3], acc[rr]);
        }
    }
#pragma unroll
    for (int rr = 0; rr < 4; ++rr) {
        float4 v = acc[rr];
        if (SILU) { v.x = silu_f(v.x); v.y = silu_f(v.y); v.z = silu_f(v.z); v.w = silu_f(v.w); }
        st4(out + (size_t)(rowbase + ry * 4 + rr) * C_DIM + cx * 4, v);
    }
}

// ---------------- GraphNorm ----------------
__global__ __launch_bounds__(256) void gn_reduce_kernel(
    const float* __restrict__ h, const int* __restrict__ start,
    const int* __restrict__ cnt, const float* __restrict__ cntf,
    const float* __restrict__ ms, float* __restrict__ meansc,
    float* __restrict__ rstd)
{
    const int g = blockIdx.x;
    const int c = threadIdx.x & 127;
    const int half = threadIdx.x >> 7;
    const int s0 = start[g];
    const int n = cnt[g];
    float sum = 0.f, sq = 0.f;
    for (int r = half; r < n; r += 2) {
        float v = h[(size_t)(s0 + r) * C_DIM + c];
        sum += v; sq += v * v;
    }
    __shared__ float ls[256], lq[256];
    ls[threadIdx.x] = sum; lq[threadIdx.x] = sq;
    __syncthreads();
    if (threadIdx.x < 128) {
        sum = ls[threadIdx.x] + ls[threadIdx.x + 128];
        sq  = lq[threadIdx.x] + lq[threadIdx.x + 128];
        const float cn = cntf[g];
        const float mean = sum / cn;
        const float msq = sq / cn;
        const float s = ms[c];
        const float var = msq - (2.0f * s - s * s) * mean * mean;
        meansc[(size_t)g * C_DIM + c] = mean * s;
        rstd[(size_t)g * C_DIM + c] = 1.0f / sqrtf(var + GN_EPS);
    }
}

__global__ __launch_bounds__(256) void gn_norm_kernel(
    const float* __restrict__ h, const int* __restrict__ batch,
    const float* __restrict__ meansc, const float* __restrict__ rstd,
    const float* __restrict__ gw, const float* __restrict__ gb,
    float* __restrict__ out)
{
    const int id = blockIdx.x * blockDim.x + threadIdx.x;
    const int row = id >> 5;
    const int c4 = (id & 31) * 4;
    if (row >= N_NODES) return;
    const int g = batch[row];
    const float4 hv = ld4(h + (size_t)row * C_DIM + c4);
    const float4 m = ld4(meansc + (size_t)g * C_DIM + c4);
    const float4 r = ld4(rstd + (size_t)g * C_DIM + c4);
    const float4 w = ld4(gw + c4);
    const float4 b = ld4(gb + c4);
    float4 o;
    o.x = fmaf((hv.x - m.x) * r.x, w.x, b.x);
    o.y = fmaf((hv.y - m.y) * r.y, w.y, b.y);
    o.z = fmaf((hv.z - m.z) * r.z, w.z, b.z);
    o.w = fmaf((hv.w - m.w) * r.w, w.w, b.w);
    st4(out + (size_t)row * C_DIM + c4, o);
}

// ---------------- launch ----------------

extern "C" void kernel_launch(void* const* d_in, const int* in_sizes, int n_in,
                              void* d_out, int out_size, void* d_ws, size_t ws_size,
                              hipStream_t stream)
{
    const float* x_in      = (const float*)d_in[0];
    const float* edge_attr = (const float*)d_in[1];
    const int*   edge_idx  = (const int*)d_in[2];
    const int*   batch     = (const int*)d_in[3];
    const float* lew       = (const float*)d_in[4];
    const float* leb       = (const float*)d_in[5];
    const float* w1        = (const float*)d_in[6];
    const float* b1        = (const float*)d_in[7];
    const float* w2        = (const float*)d_in[8];
    const float* b2        = (const float*)d_in[9];
    const float* gnw       = (const float*)d_in[10];
    const float* gnb       = (const float*)d_in[11];
    const float* gms       = (const float*)d_in[12];
    float* out = (float*)d_out;

    // workspace layout
    float* hbuf   = (float*)d_ws;                        // N*C
    float* meansc = hbuf + (size_t)N_NODES * C_DIM;      // G*C
    float* rstd   = meansc + (size_t)G_GRAPHS * C_DIM;   // G*C
    float* cntf   = rstd + (size_t)G_GRAPHS * C_DIM;     // G
    int*   cnti   = (int*)(cntf + G_GRAPHS);             // G
    int*   startg = cnti + G_GRAPHS;                     // G
    int*   deg    = startg + G_GRAPHS;                   // N
    int*   rpl    = deg + N_NODES;                       // N
    int*   bsum   = rpl + N_NODES;                       // 512
    int*   boff   = bsum + 512;                          // 512
    int*   rp     = boff + 512;                          // N+1
    int*   cursor = rp + N_NODES + 2;                    // N (+1 pad keeps csr 8B-aligned)
    int2*  csr    = (int2*)(cursor + N_NODES);           // E (8B aligned by construction)

    // GraphNorm segment bookkeeping
    zero_cnt_kernel<<<1, G_GRAPHS, 0, stream>>>(cnti);
    count_kernel<<<(N_NODES + 255) / 256, 256, 0, stream>>>(batch, cnti);
    scan_kernel<<<1, G_GRAPHS, 0, stream>>>(cnti, startg, cntf);

    // CSR build (by dst), once per call
    hipMemsetAsync(deg, 0, (size_t)N_NODES * sizeof(int), stream);
    deg_count_kernel<<<(N_EDGES + 255) / 256, 256, 0, stream>>>(edge_idx, deg);
    scanA_kernel<<<SCAN_BLOCKS, 256, 0, stream>>>(deg, rpl, bsum);
    scanB_kernel<<<1, 512, 0, stream>>>(bsum, boff);
    scanC_kernel<<<SCAN_BLOCKS, 256, 0, stream>>>(rpl, boff, rp, cursor);
    fill_kernel<<<(N_EDGES + 255) / 256, 256, 0, stream>>>(edge_idx, cursor, csr);

    const float* cur = x_in;
    for (int l = 0; l < L_LAYERS; ++l) {
        gather_kernel<<<(N_NODES * 64 + 255) / 256, 256, 0, stream>>>(
            cur, edge_attr, csr, rp, lew, leb, hbuf);
        gemm128_kernel<true><<<N_NODES / 32, 256, 0, stream>>>(
            hbuf, w1 + (size_t)l * C_DIM * C_DIM, b1 + (size_t)l * C_DIM, out);
        gemm128_kernel<false><<<N_NODES / 32, 256, 0, stream>>>(
            out, w2 + (size_t)l * C_DIM * C_DIM, b2 + (size_t)l * C_DIM, hbuf);
        gn_reduce_kernel<<<G_GRAPHS, 256, 0, stream>>>(
            hbuf, startg, cnti, cntf, gms + (size_t)l * C_DIM, meansc, rstd);
        gn_norm_kernel<<<(N_NODES * 32 + 255) / 256, 256, 0, stream>>>(
            hbuf, batch, meansc, rstd, gnw + (size_t)l * C_DIM, gnb + (size_t)l * C_DIM,
            out);
        cur = out;
    }
}

// Round 4
// 2387.466 us; speedup vs baseline: 3.8326x; 1.0461x over previous
//
#include <hip/hip_runtime.h>

#define N_NODES 100000
#define N_EDGES 1600000
#define C_DIM 128
#define EC_DIM 16
#define L_LAYERS 3
#define G_GRAPHS 256
#define GN_EPS 1e-5f
#define SCAN_BLOCKS 391   // ceil(100000/256)

__device__ __forceinline__ float silu_f(float v) {
    return v / (1.0f + __expf(-v));
}

__device__ __forceinline__ float4 ld4(const float* p) { return *(const float4*)p; }
__device__ __forceinline__ void st4(float* p, float4 v) { *(float4*)p = v; }
__device__ __forceinline__ float4 fma4(float s, float4 w, float4 a) {
    a.x = fmaf(s, w.x, a.x); a.y = fmaf(s, w.y, a.y);
    a.z = fmaf(s, w.z, a.z); a.w = fmaf(s, w.w, a.w);
    return a;
}

// ---------------- graph bookkeeping (GraphNorm segments) ----------------

__global__ void zero_cnt_kernel(int* cnt) { cnt[threadIdx.x] = 0; }

__global__ void count_kernel(const int* __restrict__ batch, int* __restrict__ cnt) {
    int i = blockIdx.x * blockDim.x + threadIdx.x;
    if (i < N_NODES) atomicAdd(&cnt[batch[i]], 1);
}

__global__ void scan_kernel(const int* __restrict__ cnt, int* __restrict__ start,
                            float* __restrict__ cntf) {
    __shared__ int s[G_GRAPHS];
    int t = threadIdx.x;
    int v = cnt[t];
    s[t] = v;
    __syncthreads();
    for (int off = 1; off < G_GRAPHS; off <<= 1) {
        int add = (t >= off) ? s[t - off] : 0;
        __syncthreads();
        s[t] += add;
        __syncthreads();
    }
    start[t] = s[t] - v;
    cntf[t] = (float)v;
}

// ---------------- CSR build (by dst) ----------------

__global__ void deg_count_kernel(const int* __restrict__ eidx, int* __restrict__ deg) {
    int e = blockIdx.x * blockDim.x + threadIdx.x;
    if (e < N_EDGES) atomicAdd(&deg[eidx[N_EDGES + e]], 1);
}

__global__ void scanA_kernel(const int* __restrict__ deg, int* __restrict__ rpl,
                             int* __restrict__ bsum) {
    __shared__ int s[256];
    int i = blockIdx.x * 256 + threadIdx.x;
    int v = (i < N_NODES) ? deg[i] : 0;
    s[threadIdx.x] = v;
    __syncthreads();
    for (int off = 1; off < 256; off <<= 1) {
        int add = (threadIdx.x >= off) ? s[threadIdx.x - off] : 0;
        __syncthreads();
        s[threadIdx.x] += add;
        __syncthreads();
    }
    if (i < N_NODES) rpl[i] = s[threadIdx.x] - v;
    if (threadIdx.x == 255) bsum[blockIdx.x] = s[255];
}

__global__ void scanB_kernel(const int* __restrict__ bsum, int* __restrict__ boff) {
    __shared__ int s[512];
    int t = threadIdx.x;
    int v = (t < SCAN_BLOCKS) ? bsum[t] : 0;
    s[t] = v;
    __syncthreads();
    for (int off = 1; off < 512; off <<= 1) {
        int add = (t >= off) ? s[t - off] : 0;
        __syncthreads();
        s[t] += add;
        __syncthreads();
    }
    if (t < SCAN_BLOCKS) boff[t] = s[t] - v;
}

__global__ void scanC_kernel(const int* __restrict__ rpl, const int* __restrict__ boff,
                             int* __restrict__ rp, int* __restrict__ cursor) {
    int i = blockIdx.x * 256 + threadIdx.x;
    if (i < N_NODES) {
        int v = rpl[i] + boff[blockIdx.x];
        rp[i] = v;
        cursor[i] = v;
    }
    if (i == 0) rp[N_NODES] = N_EDGES;
}

__global__ void fill_kernel(const int* __restrict__ eidx, int* __restrict__ cursor,
                            int2* __restrict__ csr) {
    int e = blockIdx.x * blockDim.x + threadIdx.x;
    if (e >= N_EDGES) return;
    int src = eidx[e];
    int dst = eidx[N_EDGES + e];
    int pos = atomicAdd(&cursor[dst], 1);
    csr[pos] = make_int2(src, e);
}

// ---------------- gather: h[n] = x[n] + sum_{e->n} relu(x[src]+silu(ea@W+b)) ----
// One wave per node; lane owns 2 channels. W slice in 16 NAMED float2 regs.
// NOTE: the quads are passed as explicit macro args (Q##0.x mis-lexes: "0.x"
// is a single pp-number token, so pasting forms the invalid token "A0.x").

#define DECLW(k) const float2 w##k = *(const float2*)(Wp + (k) * C_DIM);

#define EDGE_PROJ(QA, QB, QC, QD, ZX, ZY) \
    ZX = b2.x; ZY = b2.y; \
    ZX = fmaf(QA.x, w0.x,  ZX); ZY = fmaf(QA.x, w0.y,  ZY); \
    ZX = fmaf(QA.y, w1.x,  ZX); ZY = fmaf(QA.y, w1.y,  ZY); \
    ZX = fmaf(QA.z, w2.x,  ZX); ZY = fmaf(QA.z, w2.y,  ZY); \
    ZX = fmaf(QA.w, w3.x,  ZX); ZY = fmaf(QA.w, w3.y,  ZY); \
    ZX = fmaf(QB.x, w4.x,  ZX); ZY = fmaf(QB.x, w4.y,  ZY); \
    ZX = fmaf(QB.y, w5.x,  ZX); ZY = fmaf(QB.y, w5.y,  ZY); \
    ZX = fmaf(QB.z, w6.x,  ZX); ZY = fmaf(QB.z, w6.y,  ZY); \
    ZX = fmaf(QB.w, w7.x,  ZX); ZY = fmaf(QB.w, w7.y,  ZY); \
    ZX = fmaf(QC.x, w8.x,  ZX); ZY = fmaf(QC.x, w8.y,  ZY); \
    ZX = fmaf(QC.y, w9.x,  ZX); ZY = fmaf(QC.y, w9.y,  ZY); \
    ZX = fmaf(QC.z, w10.x, ZX); ZY = fmaf(QC.z, w10.y, ZY); \
    ZX = fmaf(QC.w, w11.x, ZX); ZY = fmaf(QC.w, w11.y, ZY); \
    ZX = fmaf(QD.x, w12.x, ZX); ZY = fmaf(QD.x, w12.y, ZY); \
    ZX = fmaf(QD.y, w13.x, ZX); ZY = fmaf(QD.y, w13.y, ZY); \
    ZX = fmaf(QD.z, w14.x, ZX); ZY = fmaf(QD.z, w14.y, ZY); \
    ZX = fmaf(QD.w, w15.x, ZX); ZY = fmaf(QD.w, w15.y, ZY);

__global__ __launch_bounds__(256, 4) void gather_kernel(
    const float* __restrict__ x, const float* __restrict__ ea,
    const int2* __restrict__ csr, const int* __restrict__ rp,
    const float* __restrict__ W, const float* __restrict__ bias,
    float* __restrict__ hb)
{
    const int n = (blockIdx.x * blockDim.x + threadIdx.x) >> 6;
    if (n >= N_NODES) return;
    const int lane = threadIdx.x & 63;
    const int c2 = lane * 2;
    const float* Wp = W + c2;

    DECLW(0)  DECLW(1)  DECLW(2)  DECLW(3)
    DECLW(4)  DECLW(5)  DECLW(6)  DECLW(7)
    DECLW(8)  DECLW(9)  DECLW(10) DECLW(11)
    DECLW(12) DECLW(13) DECLW(14) DECLW(15)
    const float2 b2 = *(const float2*)(bias + c2);

    float accx = 0.f, accy = 0.f;
    const int beg = rp[n], end = rp[n + 1];
    int j = beg;
    for (; j + 2 <= end; j += 2) {
        const int2 se0 = csr[j];
        const int2 se1 = csr[j + 1];
        const float* ep0 = ea + (size_t)se0.y * EC_DIM;
        const float* ep1 = ea + (size_t)se1.y * EC_DIM;
        const float4 A0 = ld4(ep0),     A1 = ld4(ep0 + 4),
                     A2 = ld4(ep0 + 8), A3 = ld4(ep0 + 12);
        const float4 B0 = ld4(ep1),     B1 = ld4(ep1 + 4),
                     B2 = ld4(ep1 + 8), B3 = ld4(ep1 + 12);
        const float2 xs0 = *(const float2*)(x + (size_t)se0.x * C_DIM + c2);
        const float2 xs1 = *(const float2*)(x + (size_t)se1.x * C_DIM + c2);
        float z0x, z0y, z1x, z1y;
        EDGE_PROJ(A0, A1, A2, A3, z0x, z0y)
        EDGE_PROJ(B0, B1, B2, B3, z1x, z1y)
        z0x = silu_f(z0x); z0y = silu_f(z0y);
        z1x = silu_f(z1x); z1y = silu_f(z1y);
        accx += fmaxf(xs0.x + z0x, 0.f) + fmaxf(xs1.x + z1x, 0.f);
        accy += fmaxf(xs0.y + z0y, 0.f) + fmaxf(xs1.y + z1y, 0.f);
    }
    if (j < end) {
        const int2 se = csr[j];
        const float* ep = ea + (size_t)se.y * EC_DIM;
        const float4 A0 = ld4(ep),     A1 = ld4(ep + 4),
                     A2 = ld4(ep + 8), A3 = ld4(ep + 12);
        const float2 xs = *(const float2*)(x + (size_t)se.x * C_DIM + c2);
        float zx, zy;
        EDGE_PROJ(A0, A1, A2, A3, zx, zy)
        accx += fmaxf(xs.x + silu_f(zx), 0.f);
        accy += fmaxf(xs.y + silu_f(zy), 0.f);
    }
    const float2 xo = *(const float2*)(x + (size_t)n * C_DIM + c2);
    *(float2*)(hb + (size_t)n * C_DIM + c2) = make_float2(xo.x + accx, xo.y + accy);
}

// ---------------- fp32 GEMM: out[N,128] = act(A[N,128] @ W[128,128] + b) ----
template<bool SILU>
__global__ __launch_bounds__(256) void gemm128_kernel(
    const float* __restrict__ A, const float* __restrict__ W,
    const float* __restrict__ bias, float* __restrict__ out)
{
    __shared__ float Wl[C_DIM * C_DIM];   // 64 KB
    const int tid = threadIdx.x;
    const int rowbase = blockIdx.x * 32;
#pragma unroll
    for (int i = 0; i < 16; ++i)
        ((float4*)Wl)[i * 256 + tid] = ((const float4*)W)[i * 256 + tid];
    __syncthreads();

    const int cx = tid & 31;
    const int ry = tid >> 5;
    const float4 bias4 = ld4(bias + cx * 4);
    float4 acc[4] = {bias4, bias4, bias4, bias4};
    const float* Ab = A + (size_t)(rowbase + ry * 4) * C_DIM;

    for (int k = 0; k < C_DIM; k += 4) {
        float4 a[4], w[4];
#pragma unroll
        for (int rr = 0; rr < 4; ++rr) a[rr] = ld4(Ab + rr * C_DIM + k);
#pragma unroll
        for (int kk = 0; kk < 4; ++kk) w[kk] = *(const float4*)&Wl[(k + kk) * C_DIM + cx * 4];
#pragma unroll
        for (int rr = 0; rr < 4; ++rr) {
            acc[rr] = fma4(a[rr].x, w[0], acc[rr]);
            acc[rr] = fma4(a[rr].y, w[1], acc[rr]);
            acc[rr] = fma4(a[rr].z, w[2], acc[rr]);
            acc[rr] = fma4(a[rr].w, w[3], acc[rr]);
        }
    }
#pragma unroll
    for (int rr = 0; rr < 4; ++rr) {
        float4 v = acc[rr];
        if (SILU) { v.x = silu_f(v.x); v.y = silu_f(v.y); v.z = silu_f(v.z); v.w = silu_f(v.w); }
        st4(out + (size_t)(rowbase + ry * 4 + rr) * C_DIM + cx * 4, v);
    }
}

// ---------------- GraphNorm ----------------
__global__ __launch_bounds__(1024) void gn_reduce_kernel(
    const float* __restrict__ h, const int* __restrict__ start,
    const int* __restrict__ cnt, const float* __restrict__ cntf,
    const float* __restrict__ ms, float* __restrict__ meansc,
    float* __restrict__ rstd)
{
    const int g = blockIdx.x;
    const int c = threadIdx.x & 127;
    const int sub = threadIdx.x >> 7;       // 0..7
    const int s0 = start[g];
    const int n = cnt[g];
    float sum = 0.f, sq = 0.f;
    for (int r = sub; r < n; r += 8) {
        float v = h[(size_t)(s0 + r) * C_DIM + c];
        sum += v; sq += v * v;
    }
    __shared__ float ls[1024], lq[1024];
    ls[threadIdx.x] = sum; lq[threadIdx.x] = sq;
    __syncthreads();
    if (threadIdx.x < 512) {
        ls[threadIdx.x] += ls[threadIdx.x + 512];
        lq[threadIdx.x] += lq[threadIdx.x + 512];
    }
    __syncthreads();
    if (threadIdx.x < 256) {
        ls[threadIdx.x] += ls[threadIdx.x + 256];
        lq[threadIdx.x] += lq[threadIdx.x + 256];
    }
    __syncthreads();
    if (threadIdx.x < 128) {
        sum = ls[threadIdx.x] + ls[threadIdx.x + 128];
        sq  = lq[threadIdx.x] + lq[threadIdx.x + 128];
        const float cn = cntf[g];
        const float mean = sum / cn;
        const float msq = sq / cn;
        const float s = ms[c];
        const float var = msq - (2.0f * s - s * s) * mean * mean;
        meansc[(size_t)g * C_DIM + c] = mean * s;
        rstd[(size_t)g * C_DIM + c] = 1.0f / sqrtf(var + GN_EPS);
    }
}

__global__ __launch_bounds__(256) void gn_norm_kernel(
    const float* __restrict__ h, const int* __restrict__ batch,
    const float* __restrict__ meansc, const float* __restrict__ rstd,
    const float* __restrict__ gw, const float* __restrict__ gb,
    float* __restrict__ out)
{
    const int id = blockIdx.x * blockDim.x + threadIdx.x;
    const int row = id >> 5;
    const int c4 = (id & 31) * 4;
    if (row >= N_NODES) return;
    const int g = batch[row];
    const float4 hv = ld4(h + (size_t)row * C_DIM + c4);
    const float4 m = ld4(meansc + (size_t)g * C_DIM + c4);
    const float4 r = ld4(rstd + (size_t)g * C_DIM + c4);
    const float4 w = ld4(gw + c4);
    const float4 b = ld4(gb + c4);
    float4 o;
    o.x = fmaf((hv.x - m.x) * r.x, w.x, b.x);
    o.y = fmaf((hv.y - m.y) * r.y, w.y, b.y);
    o.z = fmaf((hv.z - m.z) * r.z, w.z, b.z);
    o.w = fmaf((hv.w - m.w) * r.w, w.w, b.w);
    st4(out + (size_t)row * C_DIM + c4, o);
}

// ---------------- launch ----------------

extern "C" void kernel_launch(void* const* d_in, const int* in_sizes, int n_in,
                              void* d_out, int out_size, void* d_ws, size_t ws_size,
                              hipStream_t stream)
{
    const float* x_in      = (const float*)d_in[0];
    const float* edge_attr = (const float*)d_in[1];
    const int*   edge_idx  = (const int*)d_in[2];
    const int*   batch     = (const int*)d_in[3];
    const float* lew       = (const float*)d_in[4];
    const float* leb       = (const float*)d_in[5];
    const float* w1        = (const float*)d_in[6];
    const float* b1        = (const float*)d_in[7];
    const float* w2        = (const float*)d_in[8];
    const float* b2        = (const float*)d_in[9];
    const float* gnw       = (const float*)d_in[10];
    const float* gnb       = (const float*)d_in[11];
    const float* gms       = (const float*)d_in[12];
    float* out = (float*)d_out;

    // workspace layout
    float* hbuf   = (float*)d_ws;                        // N*C
    float* meansc = hbuf + (size_t)N_NODES * C_DIM;      // G*C
    float* rstd   = meansc + (size_t)G_GRAPHS * C_DIM;   // G*C
    float* cntf   = rstd + (size_t)G_GRAPHS * C_DIM;     // G
    int*   cnti   = (int*)(cntf + G_GRAPHS);             // G
    int*   startg = cnti + G_GRAPHS;                     // G
    int*   deg    = startg + G_GRAPHS;                   // N
    int*   rpl    = deg + N_NODES;                       // N
    int*   bsum   = rpl + N_NODES;                       // 512
    int*   boff   = bsum + 512;                          // 512
    int*   rp     = boff + 512;                          // N+1
    int*   cursor = rp + N_NODES + 2;                    // N
    int2*  csr    = (int2*)(cursor + N_NODES);           // E

    // GraphNorm segment bookkeeping
    zero_cnt_kernel<<<1, G_GRAPHS, 0, stream>>>(cnti);
    count_kernel<<<(N_NODES + 255) / 256, 256, 0, stream>>>(batch, cnti);
    scan_kernel<<<1, G_GRAPHS, 0, stream>>>(cnti, startg, cntf);

    // CSR build (by dst), once per call
    hipMemsetAsync(deg, 0, (size_t)N_NODES * sizeof(int), stream);
    deg_count_kernel<<<(N_EDGES + 255) / 256, 256, 0, stream>>>(edge_idx, deg);
    scanA_kernel<<<SCAN_BLOCKS, 256, 0, stream>>>(deg, rpl, bsum);
    scanB_kernel<<<1, 512, 0, stream>>>(bsum, boff);
    scanC_kernel<<<SCAN_BLOCKS, 256, 0, stream>>>(rpl, boff, rp, cursor);
    fill_kernel<<<(N_EDGES + 255) / 256, 256, 0, stream>>>(edge_idx, cursor, csr);

    const float* cur = x_in;
    for (int l = 0; l < L_LAYERS; ++l) {
        gather_kernel<<<(N_NODES * 64 + 255) / 256, 256, 0, stream>>>(
            cur, edge_attr, csr, rp, lew, leb, hbuf);
        gemm128_kernel<true><<<N_NODES / 32, 256, 0, stream>>>(
            hbuf, w1 + (size_t)l * C_DIM * C_DIM, b1 + (size_t)l * C_DIM, out);
        gemm128_kernel<false><<<N_NODES / 32, 256, 0, stream>>>(
            out, w2 + (size_t)l * C_DIM * C_DIM, b2 + (size_t)l * C_DIM, hbuf);
        gn_reduce_kernel<<<G_GRAPHS, 1024, 0, stream>>>(
            hbuf, startg, cnti, cntf, gms + (size_t)l * C_DIM, meansc, rstd);
        gn_norm_kernel<<<(N_NODES * 32 + 255) / 256, 256, 0, stream>>>(
            hbuf, batch, meansc, rstd, gnw + (size_t)l * C_DIM, gnb + (size_t)l * C_DIM,
            out);
        cur = out;
    }
}

// Round 5
// 2131.008 us; speedup vs baseline: 4.2938x; 1.1203x over previous
//
#include <hip/hip_runtime.h>

#define N_NODES 100000
#define N_EDGES 1600000
#define C_DIM 128
#define EC_DIM 16
#define L_LAYERS 3
#define G_GRAPHS 256
#define GN_EPS 1e-5f
#define SCAN_BLOCKS 391   // ceil(100000/256)

__device__ __forceinline__ float silu_f(float v) {
    return v / (1.0f + __expf(-v));
}

__device__ __forceinline__ float4 ld4(const float* p) { return *(const float4*)p; }
__device__ __forceinline__ void st4(float* p, float4 v) { *(float4*)p = v; }
__device__ __forceinline__ float4 fma4(float s, float4 w, float4 a) {
    a.x = fmaf(s, w.x, a.x); a.y = fmaf(s, w.y, a.y);
    a.z = fmaf(s, w.z, a.z); a.w = fmaf(s, w.w, a.w);
    return a;
}

// round-to-nearest-even float -> bf16 bits
__device__ __forceinline__ unsigned int f2bf(float f) {
    unsigned int u = __float_as_uint(f);
    return (u + 0x7fffu + ((u >> 16) & 1u)) >> 16;
}

// ---------------- graph bookkeeping (GraphNorm segments) ----------------

__global__ void zero_cnt_kernel(int* cnt) { cnt[threadIdx.x] = 0; }

__global__ void count_kernel(const int* __restrict__ batch, int* __restrict__ cnt) {
    int i = blockIdx.x * blockDim.x + threadIdx.x;
    if (i < N_NODES) atomicAdd(&cnt[batch[i]], 1);
}

__global__ void scan_kernel(const int* __restrict__ cnt, int* __restrict__ start,
                            float* __restrict__ cntf) {
    __shared__ int s[G_GRAPHS];
    int t = threadIdx.x;
    int v = cnt[t];
    s[t] = v;
    __syncthreads();
    for (int off = 1; off < G_GRAPHS; off <<= 1) {
        int add = (t >= off) ? s[t - off] : 0;
        __syncthreads();
        s[t] += add;
        __syncthreads();
    }
    start[t] = s[t] - v;
    cntf[t] = (float)v;
}

// ---------------- CSR build (by dst) ----------------

__global__ void deg_count_kernel(const int* __restrict__ eidx, int* __restrict__ deg) {
    int e = blockIdx.x * blockDim.x + threadIdx.x;
    if (e < N_EDGES) atomicAdd(&deg[eidx[N_EDGES + e]], 1);
}

__global__ void scanA_kernel(const int* __restrict__ deg, int* __restrict__ rpl,
                             int* __restrict__ bsum) {
    __shared__ int s[256];
    int i = blockIdx.x * 256 + threadIdx.x;
    int v = (i < N_NODES) ? deg[i] : 0;
    s[threadIdx.x] = v;
    __syncthreads();
    for (int off = 1; off < 256; off <<= 1) {
        int add = (threadIdx.x >= off) ? s[threadIdx.x - off] : 0;
        __syncthreads();
        s[threadIdx.x] += add;
        __syncthreads();
    }
    if (i < N_NODES) rpl[i] = s[threadIdx.x] - v;
    if (threadIdx.x == 255) bsum[blockIdx.x] = s[255];
}

__global__ void scanB_kernel(const int* __restrict__ bsum, int* __restrict__ boff) {
    __shared__ int s[512];
    int t = threadIdx.x;
    int v = (t < SCAN_BLOCKS) ? bsum[t] : 0;
    s[t] = v;
    __syncthreads();
    for (int off = 1; off < 512; off <<= 1) {
        int add = (t >= off) ? s[t - off] : 0;
        __syncthreads();
        s[t] += add;
        __syncthreads();
    }
    if (t < SCAN_BLOCKS) boff[t] = s[t] - v;
}

__global__ void scanC_kernel(const int* __restrict__ rpl, const int* __restrict__ boff,
                             int* __restrict__ rp, int* __restrict__ cursor) {
    int i = blockIdx.x * 256 + threadIdx.x;
    if (i < N_NODES) {
        int v = rpl[i] + boff[blockIdx.x];
        rp[i] = v;
        cursor[i] = v;
    }
    if (i == 0) rp[N_NODES] = N_EDGES;
}

__global__ void fill_kernel(const int* __restrict__ eidx, int* __restrict__ cursor,
                            int2* __restrict__ csr) {
    int e = blockIdx.x * blockDim.x + threadIdx.x;
    if (e >= N_EDGES) return;
    int src = eidx[e];
    int dst = eidx[N_EDGES + e];
    int pos = atomicAdd(&cursor[dst], 1);
    csr[pos] = make_int2(src, e);
}

// ---------------- edge projection, once: e_csr[pos] = bf16(silu(ea@W+b)) ----
// Half-wave (32 lanes) per edge in CSR order; lane owns 4 channels.
// W slice in 16 named float4 regs, amortized over a grid-stride loop.

#define DECLW4(k) const float4 W##k = ld4(Wp + (k) * C_DIM);

#define PROJ4(QA, QB, QC, QD, Z) \
    Z = b4; \
    Z = fma4(QA.x, W0,  Z); Z = fma4(QA.y, W1,  Z); \
    Z = fma4(QA.z, W2,  Z); Z = fma4(QA.w, W3,  Z); \
    Z = fma4(QB.x, W4,  Z); Z = fma4(QB.y, W5,  Z); \
    Z = fma4(QB.z, W6,  Z); Z = fma4(QB.w, W7,  Z); \
    Z = fma4(QC.x, W8,  Z); Z = fma4(QC.y, W9,  Z); \
    Z = fma4(QC.z, W10, Z); Z = fma4(QC.w, W11, Z); \
    Z = fma4(QD.x, W12, Z); Z = fma4(QD.y, W13, Z); \
    Z = fma4(QD.z, W14, Z); Z = fma4(QD.w, W15, Z);

__global__ __launch_bounds__(256, 4) void eproj_kernel(
    const float* __restrict__ ea, const int2* __restrict__ csr,
    const float* __restrict__ W, const float* __restrict__ bias,
    uint2* __restrict__ ecsr)
{
    const int l32 = threadIdx.x & 31;
    const int c4 = l32 * 4;
    const float* Wp = W + c4;
    DECLW4(0)  DECLW4(1)  DECLW4(2)  DECLW4(3)
    DECLW4(4)  DECLW4(5)  DECLW4(6)  DECLW4(7)
    DECLW4(8)  DECLW4(9)  DECLW4(10) DECLW4(11)
    DECLW4(12) DECLW4(13) DECLW4(14) DECLW4(15)
    const float4 b4 = ld4(bias + c4);

    int hw = (blockIdx.x * blockDim.x + threadIdx.x) >> 5;
    const int nhw = (gridDim.x * blockDim.x) >> 5;
    for (int pos = hw; pos < N_EDGES; pos += nhw) {
        const int e = csr[pos].y;
        const float* ep = ea + (size_t)e * EC_DIM;
        const float4 A0 = ld4(ep),     A1 = ld4(ep + 4),
                     A2 = ld4(ep + 8), A3 = ld4(ep + 12);
        float4 z;
        PROJ4(A0, A1, A2, A3, z)
        z.x = silu_f(z.x); z.y = silu_f(z.y);
        z.z = silu_f(z.z); z.w = silu_f(z.w);
        uint2 o;
        o.x = f2bf(z.x) | (f2bf(z.y) << 16);
        o.y = f2bf(z.z) | (f2bf(z.w) << 16);
        ecsr[(size_t)pos * 32 + l32] = o;
    }
}

// ---------------- streaming gather: h[n] = x[n] + sum relu(x[src]+e_csr) ----
// One wave per node; lanes 0-31 take even CSR slots, 32-63 odd. Lane owns 4
// channels. e_csr rows stream sequentially (256 B/edge, 512 B/wave-iter).
__global__ __launch_bounds__(256) void gather2_kernel(
    const float* __restrict__ x, const uint2* __restrict__ ecsr,
    const int2* __restrict__ csr, const int* __restrict__ rp,
    float* __restrict__ hb)
{
    const int n = (blockIdx.x * blockDim.x + threadIdx.x) >> 6;
    if (n >= N_NODES) return;
    const int lane = threadIdx.x & 63;
    const int half = lane >> 5;
    const int c4 = (lane & 31) * 4;

    float4 acc = make_float4(0.f, 0.f, 0.f, 0.f);
    const int beg = rp[n], end = rp[n + 1];
    for (int j = beg + half; j < end; j += 2) {
        const int src = csr[j].x;
        const uint2 eb = ecsr[(size_t)j * 32 + (lane & 31)];
        const float4 xs = ld4(x + (size_t)src * C_DIM + c4);
        const float e0 = __uint_as_float(eb.x << 16);
        const float e1 = __uint_as_float(eb.x & 0xffff0000u);
        const float e2 = __uint_as_float(eb.y << 16);
        const float e3 = __uint_as_float(eb.y & 0xffff0000u);
        acc.x += fmaxf(xs.x + e0, 0.f);
        acc.y += fmaxf(xs.y + e1, 0.f);
        acc.z += fmaxf(xs.z + e2, 0.f);
        acc.w += fmaxf(xs.w + e3, 0.f);
    }
    // combine the two half-wave partials
    acc.x += __shfl_xor(acc.x, 32);
    acc.y += __shfl_xor(acc.y, 32);
    acc.z += __shfl_xor(acc.z, 32);
    acc.w += __shfl_xor(acc.w, 32);
    if (half == 0) {
        const float4 xo = ld4(x + (size_t)n * C_DIM + c4);
        st4(hb + (size_t)n * C_DIM + c4,
            make_float4(xo.x + acc.x, xo.y + acc.y, xo.z + acc.z, xo.w + acc.w));
    }
}

// ---------------- fallback gather (round-4 path, recomputes e per layer) ----

#define DECLW(k) const float2 w##k = *(const float2*)(Wp + (k) * C_DIM);

#define EDGE_PROJ(QA, QB, QC, QD, ZX, ZY) \
    ZX = b2.x; ZY = b2.y; \
    ZX = fmaf(QA.x, w0.x,  ZX); ZY = fmaf(QA.x, w0.y,  ZY); \
    ZX = fmaf(QA.y, w1.x,  ZX); ZY = fmaf(QA.y, w1.y,  ZY); \
    ZX = fmaf(QA.z, w2.x,  ZX); ZY = fmaf(QA.z, w2.y,  ZY); \
    ZX = fmaf(QA.w, w3.x,  ZX); ZY = fmaf(QA.w, w3.y,  ZY); \
    ZX = fmaf(QB.x, w4.x,  ZX); ZY = fmaf(QB.x, w4.y,  ZY); \
    ZX = fmaf(QB.y, w5.x,  ZX); ZY = fmaf(QB.y, w5.y,  ZY); \
    ZX = fmaf(QB.z, w6.x,  ZX); ZY = fmaf(QB.z, w6.y,  ZY); \
    ZX = fmaf(QB.w, w7.x,  ZX); ZY = fmaf(QB.w, w7.y,  ZY); \
    ZX = fmaf(QC.x, w8.x,  ZX); ZY = fmaf(QC.x, w8.y,  ZY); \
    ZX = fmaf(QC.y, w9.x,  ZX); ZY = fmaf(QC.y, w9.y,  ZY); \
    ZX = fmaf(QC.z, w10.x, ZX); ZY = fmaf(QC.z, w10.y, ZY); \
    ZX = fmaf(QC.w, w11.x, ZX); ZY = fmaf(QC.w, w11.y, ZY); \
    ZX = fmaf(QD.x, w12.x, ZX); ZY = fmaf(QD.x, w12.y, ZY); \
    ZX = fmaf(QD.y, w13.x, ZX); ZY = fmaf(QD.y, w13.y, ZY); \
    ZX = fmaf(QD.z, w14.x, ZX); ZY = fmaf(QD.z, w14.y, ZY); \
    ZX = fmaf(QD.w, w15.x, ZX); ZY = fmaf(QD.w, w15.y, ZY);

__global__ __launch_bounds__(256, 4) void gather_kernel(
    const float* __restrict__ x, const float* __restrict__ ea,
    const int2* __restrict__ csr, const int* __restrict__ rp,
    const float* __restrict__ W, const float* __restrict__ bias,
    float* __restrict__ hb)
{
    const int n = (blockIdx.x * blockDim.x + threadIdx.x) >> 6;
    if (n >= N_NODES) return;
    const int lane = threadIdx.x & 63;
    const int c2 = lane * 2;
    const float* Wp = W + c2;
    DECLW(0)  DECLW(1)  DECLW(2)  DECLW(3)
    DECLW(4)  DECLW(5)  DECLW(6)  DECLW(7)
    DECLW(8)  DECLW(9)  DECLW(10) DECLW(11)
    DECLW(12) DECLW(13) DECLW(14) DECLW(15)
    const float2 b2 = *(const float2*)(bias + c2);

    float accx = 0.f, accy = 0.f;
    const int beg = rp[n], end = rp[n + 1];
    for (int j = beg; j < end; ++j) {
        const int2 se = csr[j];
        const float* ep = ea + (size_t)se.y * EC_DIM;
        const float4 A0 = ld4(ep),     A1 = ld4(ep + 4),
                     A2 = ld4(ep + 8), A3 = ld4(ep + 12);
        const float2 xs = *(const float2*)(x + (size_t)se.x * C_DIM + c2);
        float zx, zy;
        EDGE_PROJ(A0, A1, A2, A3, zx, zy)
        accx += fmaxf(xs.x + silu_f(zx), 0.f);
        accy += fmaxf(xs.y + silu_f(zy), 0.f);
    }
    const float2 xo = *(const float2*)(x + (size_t)n * C_DIM + c2);
    *(float2*)(hb + (size_t)n * C_DIM + c2) = make_float2(xo.x + accx, xo.y + accy);
}

// ---------------- fp32 GEMM: out[N,128] = act(A[N,128] @ W[128,128] + b) ----
template<bool SILU>
__global__ __launch_bounds__(256) void gemm128_kernel(
    const float* __restrict__ A, const float* __restrict__ W,
    const float* __restrict__ bias, float* __restrict__ out)
{
    __shared__ float Wl[C_DIM * C_DIM];   // 64 KB
    const int tid = threadIdx.x;
    const int rowbase = blockIdx.x * 32;
#pragma unroll
    for (int i = 0; i < 16; ++i)
        ((float4*)Wl)[i * 256 + tid] = ((const float4*)W)[i * 256 + tid];
    __syncthreads();

    const int cx = tid & 31;
    const int ry = tid >> 5;
    const float4 bias4 = ld4(bias + cx * 4);
    float4 acc[4] = {bias4, bias4, bias4, bias4};
    const float* Ab = A + (size_t)(rowbase + ry * 4) * C_DIM;

    for (int k = 0; k < C_DIM; k += 4) {
        float4 a[4], w[4];
#pragma unroll
        for (int rr = 0; rr < 4; ++rr) a[rr] = ld4(Ab + rr * C_DIM + k);
#pragma unroll
        for (int kk = 0; kk < 4; ++kk) w[kk] = *(const float4*)&Wl[(k + kk) * C_DIM + cx * 4];
#pragma unroll
        for (int rr = 0; rr < 4; ++rr) {
            acc[rr] = fma4(a[rr].x, w[0], acc[rr]);
            acc[rr] = fma4(a[rr].y, w[1], acc[rr]);
            acc[rr] = fma4(a[rr].z, w[2], acc[rr]);
            acc[rr] = fma4(a[rr].w, w[3], acc[rr]);
        }
    }
#pragma unroll
    for (int rr = 0; rr < 4; ++rr) {
        float4 v = acc[rr];
        if (SILU) { v.x = silu_f(v.x); v.y = silu_f(v.y); v.z = silu_f(v.z); v.w = silu_f(v.w); }
        st4(out + (size_t)(rowbase + ry * 4 + rr) * C_DIM + cx * 4, v);
    }
}

// ---------------- GraphNorm ----------------
__global__ __launch_bounds__(1024) void gn_reduce_kernel(
    const float* __restrict__ h, const int* __restrict__ start,
    const int* __restrict__ cnt, const float* __restrict__ cntf,
    const float* __restrict__ ms, float* __restrict__ meansc,
    float* __restrict__ rstd)
{
    const int g = blockIdx.x;
    const int c = threadIdx.x & 127;
    const int sub = threadIdx.x >> 7;       // 0..7
    const int s0 = start[g];
    const int n = cnt[g];
    float sum = 0.f, sq = 0.f;
    for (int r = sub; r < n; r += 8) {
        float v = h[(size_t)(s0 + r) * C_DIM + c];
        sum += v; sq += v * v;
    }
    __shared__ float ls[1024], lq[1024];
    ls[threadIdx.x] = sum; lq[threadIdx.x] = sq;
    __syncthreads();
    if (threadIdx.x < 512) {
        ls[threadIdx.x] += ls[threadIdx.x + 512];
        lq[threadIdx.x] += lq[threadIdx.x + 512];
    }
    __syncthreads();
    if (threadIdx.x < 256) {
        ls[threadIdx.x] += ls[threadIdx.x + 256];
        lq[threadIdx.x] += lq[threadIdx.x + 256];
    }
    __syncthreads();
    if (threadIdx.x < 128) {
        sum = ls[threadIdx.x] + ls[threadIdx.x + 128];
        sq  = lq[threadIdx.x] + lq[threadIdx.x + 128];
        const float cn = cntf[g];
        const float mean = sum / cn;
        const float msq = sq / cn;
        const float s = ms[c];
        const float var = msq - (2.0f * s - s * s) * mean * mean;
        meansc[(size_t)g * C_DIM + c] = mean * s;
        rstd[(size_t)g * C_DIM + c] = 1.0f / sqrtf(var + GN_EPS);
    }
}

__global__ __launch_bounds__(256) void gn_norm_kernel(
    const float* __restrict__ h, const int* __restrict__ batch,
    const float* __restrict__ meansc, const float* __restrict__ rstd,
    const float* __restrict__ gw, const float* __restrict__ gb,
    float* __restrict__ out)
{
    const int id = blockIdx.x * blockDim.x + threadIdx.x;
    const int row = id >> 5;
    const int c4 = (id & 31) * 4;
    if (row >= N_NODES) return;
    const int g = batch[row];
    const float4 hv = ld4(h + (size_t)row * C_DIM + c4);
    const float4 m = ld4(meansc + (size_t)g * C_DIM + c4);
    const float4 r = ld4(rstd + (size_t)g * C_DIM + c4);
    const float4 w = ld4(gw + c4);
    const float4 b = ld4(gb + c4);
    float4 o;
    o.x = fmaf((hv.x - m.x) * r.x, w.x, b.x);
    o.y = fmaf((hv.y - m.y) * r.y, w.y, b.y);
    o.z = fmaf((hv.z - m.z) * r.z, w.z, b.z);
    o.w = fmaf((hv.w - m.w) * r.w, w.w, b.w);
    st4(out + (size_t)row * C_DIM + c4, o);
}

// ---------------- launch ----------------

extern "C" void kernel_launch(void* const* d_in, const int* in_sizes, int n_in,
                              void* d_out, int out_size, void* d_ws, size_t ws_size,
                              hipStream_t stream)
{
    const float* x_in      = (const float*)d_in[0];
    const float* edge_attr = (const float*)d_in[1];
    const int*   edge_idx  = (const int*)d_in[2];
    const int*   batch     = (const int*)d_in[3];
    const float* lew       = (const float*)d_in[4];
    const float* leb       = (const float*)d_in[5];
    const float* w1        = (const float*)d_in[6];
    const float* b1        = (const float*)d_in[7];
    const float* w2        = (const float*)d_in[8];
    const float* b2        = (const float*)d_in[9];
    const float* gnw       = (const float*)d_in[10];
    const float* gnb       = (const float*)d_in[11];
    const float* gms       = (const float*)d_in[12];
    float* out = (float*)d_out;

    // workspace layout
    float* hbuf   = (float*)d_ws;                        // N*C
    float* meansc = hbuf + (size_t)N_NODES * C_DIM;      // G*C
    float* rstd   = meansc + (size_t)G_GRAPHS * C_DIM;   // G*C
    float* cntf   = rstd + (size_t)G_GRAPHS * C_DIM;     // G
    int*   cnti   = (int*)(cntf + G_GRAPHS);             // G
    int*   startg = cnti + G_GRAPHS;                     // G
    int*   deg    = startg + G_GRAPHS;                   // N
    int*   rpl    = deg + N_NODES;                       // N
    int*   bsum   = rpl + N_NODES;                       // 512
    int*   boff   = bsum + 512;                          // 512
    int*   rp     = boff + 512;                          // N+1
    int*   cursor = rp + N_NODES + 2;                    // N
    int2*  csr    = (int2*)(cursor + N_NODES);           // E (8B aligned)
    uint2* ecsr   = (uint2*)(csr + N_EDGES);             // E*C bf16 = E*32 uint2

    const size_t need = (size_t)((char*)(ecsr + (size_t)N_EDGES * 32) - (char*)d_ws);
    const bool big = ws_size >= need;

    // GraphNorm segment bookkeeping
    zero_cnt_kernel<<<1, G_GRAPHS, 0, stream>>>(cnti);
    count_kernel<<<(N_NODES + 255) / 256, 256, 0, stream>>>(batch, cnti);
    scan_kernel<<<1, G_GRAPHS, 0, stream>>>(cnti, startg, cntf);

    // CSR build (by dst), once per call
    hipMemsetAsync(deg, 0, (size_t)N_NODES * sizeof(int), stream);
    deg_count_kernel<<<(N_EDGES + 255) / 256, 256, 0, stream>>>(edge_idx, deg);
    scanA_kernel<<<SCAN_BLOCKS, 256, 0, stream>>>(deg, rpl, bsum);
    scanB_kernel<<<1, 512, 0, stream>>>(bsum, boff);
    scanC_kernel<<<SCAN_BLOCKS, 256, 0, stream>>>(rpl, boff, rp, cursor);
    fill_kernel<<<(N_EDGES + 255) / 256, 256, 0, stream>>>(edge_idx, cursor, csr);

    if (big) {
        eproj_kernel<<<2048, 256, 0, stream>>>(edge_attr, csr, lew, leb, ecsr);
    }

    const float* cur = x_in;
    for (int l = 0; l < L_LAYERS; ++l) {
        if (big) {
            gather2_kernel<<<(N_NODES * 64 + 255) / 256, 256, 0, stream>>>(
                cur, ecsr, csr, rp, hbuf);
        } else {
            gather_kernel<<<(N_NODES * 64 + 255) / 256, 256, 0, stream>>>(
                cur, edge_attr, csr, rp, lew, leb, hbuf);
        }
        gemm128_kernel<true><<<N_NODES / 32, 256, 0, stream>>>(
            hbuf, w1 + (size_t)l * C_DIM * C_DIM, b1 + (size_t)l * C_DIM, out);
        gemm128_kernel<false><<<N_NODES / 32, 256, 0, stream>>>(
            out, w2 + (size_t)l * C_DIM * C_DIM, b2 + (size_t)l * C_DIM, hbuf);
        gn_reduce_kernel<<<G_GRAPHS, 1024, 0, stream>>>(
            hbuf, startg, cnti, cntf, gms + (size_t)l * C_DIM, meansc, rstd);
        gn_norm_kernel<<<(N_NODES * 32 + 255) / 256, 256, 0, stream>>>(
            hbuf, batch, meansc, rstd, gnw + (size_t)l * C_DIM, gnb + (size_t)l * C_DIM,
            out);
        cur = out;
    }
}